// Round 4
// baseline (293.178 us; speedup 1.0000x reference)
//
#include <hip/hip_runtime.h>

#define N_ROWS   524288
#define W_BINS   101
#define EPS_F    1e-3f
#define RPB      64                    // rows per block (one 64x101 tile)
#define NBLK     (N_ROWS / RPB)        // 8192 blocks
#define TILE_F   (RPB * W_BINS)        // 6464 floats per tile (25,856 B LDS)
#define PHASE_F  (TILE_F / 2)          // 3232 floats = 12,928 B (16B aligned)
#define THREADS  256                   // 4 waves

typedef const float __attribute__((address_space(1)))* gptr_t;
typedef float __attribute__((address_space(3)))* sptr_t;

// One block = one 64-row tile, processed as TWO 32-row phases, double-buffered
// inside the single LDS tile:
//   DMA-A ; barrier(drain A) ; issue DMA-B ; compute A ; barrier(drain B) ; compute B
// Phase-B loads fly under compute-A, so the second vmcnt(0) drain is ~free.
// 32 rows / 256 threads => each row owned by a lane OCTET (h = lane bits 3..5,
// combine = shfl_xor 8/16/32). Same 25.9 KB LDS -> 6 blocks/CU, 24 waves/CU.
__global__ __launch_bounds__(THREADS) void mrl_main(const float* __restrict__ x,
                                                    const int* __restrict__ tgt,
                                                    float4* __restrict__ partial) {
    __shared__ float  sm[TILE_F];
    __shared__ float4 wsum[4];
    const int tid  = threadIdx.x;                // 0..255
    const int wv   = tid >> 6;                   // wave 0..3
    const int lane = tid & 63;
    const int rl   = lane & 7;                   // row-in-wave 0..7
    const int h    = lane >> 3;                  // octet slot 0..7
    const float* gbase = x + (size_t)blockIdx.x * TILE_F;

    // ---- DMA phase 0: floats [0, 3232). 3 full 1KiB-chunk instrs + 40-lane tail.
    #pragma unroll
    for (int q = 0; q < 3; ++q) {
        __builtin_amdgcn_global_load_lds((gptr_t)(gbase + q * 1024 + tid * 4),
                                         (sptr_t)(sm + q * 1024 + (wv << 8)), 16, 0, 0);
    }
    if (tid < 40) {
        __builtin_amdgcn_global_load_lds((gptr_t)(gbase + 3072 + tid * 4),
                                         (sptr_t)(sm + 3072), 16, 0, 0);
    }

    // Targets for both phases, issued early (in flight with the DMA).
    const int rbase = blockIdx.x * RPB + (wv << 3) + rl;
    const int t0 = tgt[rbase];                   // phase-0 row
    const int t1 = tgt[rbase + 32];              // phase-1 row

    // Octet column ownership: h<5 own 13 cols, h>=5 own 12. cb={0,13,26,39,52,65,77,89}
    const int  cb    = (h < 5) ? h * 13 : 65 + (h - 5) * 12;
    const bool extra = (h < 5);                  // owns a 13th column

    float acc_sq = 0.f, acc_rc = 0.f;
    int   acc_k  = 0;

    auto do_phase = [&](int p, int t) {
        const float* rp = sm + p * PHASE_F + ((wv << 3) + rl) * W_BINS + cb;

        // Pass 1: e_i = exp(x_i) in registers; se, sum(e*a), e_gt.
        float e[13];
        float se0 = 0.f, se1 = 0.f, sa0 = 0.f, sa1 = 0.f, eg = 0.f;
        #pragma unroll
        for (int i = 0; i < 12; i += 2) {
            float E0 = __expf(rp[i]);
            float E1 = __expf(rp[i + 1]);
            e[i] = E0; e[i + 1] = E1;
            se0 += E0; sa0 += E0 * (float)(cb + i);
            se1 += E1; sa1 += E1 * (float)(cb + i + 1);
            eg = (cb + i     == t) ? E0 : eg;
            eg = (cb + i + 1 == t) ? E1 : eg;
        }
        if (extra) {
            float E = __expf(rp[12]); e[12] = E;
            se0 += E; sa0 += E * (float)(cb + 12);
            eg = (cb + 12 == t) ? E : eg;
        }
        float se  = se0 + se1;
        float sea = sa0 + sa1;

        // Octet combine over lane bits 3..5; partners add exact 0 to eg.
        se  += __shfl_xor(se, 8);  se  += __shfl_xor(se, 16);  se  += __shfl_xor(se, 32);
        sea += __shfl_xor(sea, 8); sea += __shfl_xor(sea, 16); sea += __shfl_xor(sea, 32);
        eg  += __shfl_xor(eg, 8);  eg  += __shfl_xor(eg, 16);  eg  += __shfl_xor(eg, 32);
        const float egt = eg;                    // bit-exact e[t]
        const float inv = __builtin_amdgcn_rcpf(se);

        if (h == 0) {                            // mean-loss once per row
            float d = sea * inv - (float)t;
            acc_sq += d * d;
        }

        // Pass 2: pure-register. e-space compare is scale-invariant; i==t -> not lt.
        float rc0 = 0.f, rc1 = 0.f;
        int   k   = 0;
        #pragma unroll
        for (int i = 0; i < 12; i += 2) {
            float E0 = e[i], E1 = e[i + 1];
            bool  l0 = E0 < egt, l1 = E1 < egt;
            float q0 = (l0 ? E0 * inv : 0.f) + EPS_F;
            float q1 = (l1 ? E1 * inv : 0.f) + EPS_F;
            rc0 -= q0 * __logf(q0);
            rc1 -= q1 * __logf(q1);
            k   += (l0 ? 0 : 1) + (l1 ? 0 : 1);
        }
        if (extra) {
            float E = e[12];
            bool  l = E < egt;
            float q = (l ? E * inv : 0.f) + EPS_F;
            rc0 -= q * __logf(q);
            k   += l ? 0 : 1;
        }
        acc_rc += rc0 + rc1;
        acc_k  += k;
    };

    __syncthreads();                             // drain: phase-0 tile visible

    // ---- Issue DMA phase 1 NOW; it flies under compute of phase 0.
    #pragma unroll
    for (int q = 0; q < 3; ++q) {
        __builtin_amdgcn_global_load_lds((gptr_t)(gbase + PHASE_F + q * 1024 + tid * 4),
                                         (sptr_t)(sm + PHASE_F + q * 1024 + (wv << 8)), 16, 0, 0);
    }
    if (tid < 40) {
        __builtin_amdgcn_global_load_lds((gptr_t)(gbase + PHASE_F + 3072 + tid * 4),
                                         (sptr_t)(sm + PHASE_F + 3072), 16, 0, 0);
    }

    do_phase(0, t0);                             // overlaps phase-1 DMA

    __syncthreads();                             // drain: phase-1 visible (~free)

    do_phase(1, t1);

    float sq = acc_sq, rc = acc_rc, kf = (float)acc_k;   // k <= 26/lane, exact
    #pragma unroll
    for (int off = 32; off >= 1; off >>= 1) {
        sq += __shfl_xor(sq, off);
        rc += __shfl_xor(rc, off);
        kf += __shfl_xor(kf, off);
    }
    if ((tid & 63) == 0) wsum[wv] = make_float4(sq, rc, kf, 0.f);
    __syncthreads();
    if (tid == 0) {
        float4 a = wsum[0], b = wsum[1], c = wsum[2], d = wsum[3];
        partial[blockIdx.x] = make_float4(a.x + b.x + c.x + d.x,
                                          a.y + b.y + c.y + d.y,
                                          a.z + b.z + c.z + d.z, 0.f);
    }
}

__global__ __launch_bounds__(1024) void mrl_reduce(const float4* __restrict__ partial,
                                                   float* __restrict__ out) {
    double s = 0.0, r = 0.0, k = 0.0;
    #pragma unroll
    for (int i = 0; i < 8; ++i) {                // 8192 = 1024 * 8
        float4 v = partial[threadIdx.x + (i << 10)];
        s += (double)v.x; r += (double)v.y; k += (double)v.z;
    }
    #pragma unroll
    for (int off = 32; off >= 1; off >>= 1) {
        s += __shfl_xor(s, off);
        r += __shfl_xor(r, off);
        k += __shfl_xor(k, off);
    }
    __shared__ double sd[48];
    const int w = threadIdx.x >> 6;              // 16 waves
    if ((threadIdx.x & 63) == 0) { sd[w * 3 + 0] = s; sd[w * 3 + 1] = r; sd[w * 3 + 2] = k; }
    __syncthreads();
    if (threadIdx.x == 0) {
        double S = 0.0, R = 0.0, K = 0.0;
        #pragma unroll
        for (int i = 0; i < 16; ++i) { S += sd[i * 3]; R += sd[i * 3 + 1]; K += sd[i * 3 + 2]; }
        const double n = (double)N_ROWS;
        out[0] = (float)(0.1  * (S / n));        // LAMBDA_1 * mean_loss (0.2 * 0.5)
        out[1] = (float)(0.05 * (R / n));        // LAMBDA_2 * residue_loss
        out[2] = (float)(K / n);                 // batch_average_K
    }
}

extern "C" void kernel_launch(void* const* d_in, const int* in_sizes, int n_in,
                              void* d_out, int out_size, void* d_ws, size_t ws_size,
                              hipStream_t stream) {
    const float* x   = (const float*)d_in[0];
    const int*   tgt = (const int*)d_in[1];
    float*  out     = (float*)d_out;
    float4* partial = (float4*)d_ws;    // 8192 * 16 B = 128 KiB, well under ws_size

    mrl_main<<<NBLK, THREADS, 0, stream>>>(x, tgt, partial);
    mrl_reduce<<<1, 1024, 0, stream>>>(partial, out);
}